// Round 1
// baseline (134.436 us; speedup 1.0000x reference)
//
#include <hip/hip_runtime.h>
#include <stdint.h>

#define EPSN 1e-12f

typedef float f32x16 __attribute__((ext_vector_type(16)));
typedef float f32x4 __attribute__((ext_vector_type(4)));
typedef __bf16 bf16x8 __attribute__((ext_vector_type(8)));

// ---- bf16 helpers (round-to-nearest-even) ----
__device__ __forceinline__ unsigned short f2bf(float f) {
  union { float f; unsigned int u; } v; v.f = f;
  unsigned int u = v.u + 0x7FFFu + ((v.u >> 16) & 1u);
  return (unsigned short)(u >> 16);
}

// ---- workspace layout (ushort offsets) ----
// Fragment-major packed weights for 32x32x16 MFMA, K padded 258(+bias)->272:
//   addr = ((tile*NKS + ks)*64 + hi*32 + col)*8 + j
//   value = W[o = tile*32 + col][k = ks*16 + hi*8 + j]  (k=258 bias, >258 zero)
#define NKS 17
#define WQF_OFF 0
#define WKF_OFF (32 * NKS * 64 * 8)
#define WVP_OFF (2 * 32 * NKS * 64 * 8)

// =====================================================================
// prep: blocks [0,512) pack wq/wk (4 o-rows each); [512,1536) WVt.
// =====================================================================
__global__ __launch_bounds__(256) void prep_kernel(
    const float* __restrict__ wq, const float* __restrict__ bq,
    const float* __restrict__ wk, const float* __restrict__ bk,
    const float* __restrict__ v, const float* __restrict__ wout,
    unsigned short* __restrict__ wsp) {
  int bid = blockIdx.x;
  if (bid < 512) {
    int isK = bid >= 256;
    int ob = (bid & 255) * 4;
    const float* w = isK ? wk : wq;
    const float* bb = isK ? bk : bq;
    unsigned short* dst = wsp + (isK ? WKF_OFF : WQF_OFF);
    // k 0..257 as 129 float2 per row
    for (int i = threadIdx.x; i < 4 * 129; i += 256) {
      int r = i / 129, q = i - r * 129;
      int o = ob + r, k = q * 2;
      float2 w2 = *(const float2*)(w + o * 258 + k);
      int g = o >> 5, col = o & 31;
      int ks = k >> 4, hi = (k >> 3) & 1, j = k & 7;
      uint32_t pk = (uint32_t)f2bf(w2.x) | ((uint32_t)f2bf(w2.y) << 16);
      *(uint32_t*)(dst + (((g * NKS + ks) * 64 + hi * 32 + col) << 3) + j) = pk;
    }
    // k 258 (bias) and 259..271 (zero)
    for (int i = threadIdx.x; i < 4 * 14; i += 256) {
      int r = i / 14, kk = 258 + (i - r * 14);
      int o = ob + r;
      int g = o >> 5, col = o & 31;
      int ks = kk >> 4, hi = (kk >> 3) & 1, j = kk & 7;
      dst[(((g * NKS + ks) * 64 + hi * 32 + col) << 3) + j] =
          (kk == 258) ? f2bf(bb[o]) : (unsigned short)0;
    }
  } else {
    int idx = (bid - 512) * 256 + threadIdx.x;  // [0, 262144)
    int fc = idx & 15, m = (idx >> 4) & 63, o = idx >> 10;
    const f32x4* wo = (const f32x4*)(wout + o * 256 + fc * 16);
    const f32x4* vm = (const f32x4*)(v + m * 256 + fc * 16);
    float s = 0.f;
#pragma unroll
    for (int f = 0; f < 4; ++f) {
      f32x4 a = wo[f], bvv = vm[f];
      s += a[0]*bvv[0] + a[1]*bvv[1] + a[2]*bvv[2] + a[3]*bvv[3];
    }
    s += __shfl_xor(s, 1, 64);
    s += __shfl_xor(s, 2, 64);
    s += __shfl_xor(s, 4, 64);
    s += __shfl_xor(s, 8, 64);
    if (fc == 0) wsp[WVP_OFF + o * 64 + m] = f2bf(s);
  }
}

// =====================================================================
// fused: 64 px/block, 256 blocks, 16 waves, 1 block/CU (~52KB LDS).
// A-stream loads go global(L2)->VGPR directly (zero reuse => no LDS
// staging), depth-1 register prefetch ring, compiler-managed waitcnt.
// K padded to 272 (17 slices of 16).
// =====================================================================
#define KP 296   // xp row stride in shorts
#define QS 66    // qbar row stride (floats)
#define AT 72    // attnM row stride (shorts)

__global__ __launch_bounds__(1024, 4) void fused_kernel(
    const float* __restrict__ x, const float* __restrict__ pos,
    const unsigned short* __restrict__ wsp, const float* __restrict__ bout,
    float* __restrict__ out) {
  __shared__ __align__(16) unsigned short xp[64 * KP];         // 37888 B
  __shared__ __align__(16) float qbarL[16 * QS];               // 4224 B
  __shared__ __align__(16) unsigned short attnM[64 * AT];      // 9216 B
  __shared__ float boutL[256];                                 // 1024 B

  const int tid = threadIdx.x;
  const int lane = tid & 63;
  const int wid = __builtin_amdgcn_readfirstlane(tid >> 6);
  const int px = lane & 31, q2 = lane >> 5;
  const int P0 = blockIdx.x * 64;
  const int b = P0 >> 12, s0 = P0 & 4095;

  // Per-wave A-stream bases (tile0 = 2*wid, tile1 = 2*wid+1; +lane frag)
  const int wtoff = (2 * wid) * NKS * 512 + lane * 8;
  const unsigned short* wqf = wsp + WQF_OFF + wtoff;
  const unsigned short* wkf = wsp + WKF_OFF + wtoff;

  // q-phase ks=0 preload: HBM/L3 latency hides behind the staging phase.
  bf16x8 A0 = *(const bf16x8*)(wqf);
  bf16x8 A1 = *(const bf16x8*)(wqf + NKS * 512);

  // ---- stage xp[p][c]: lanes along pixels => 256B coalesced rows ----
  uint32_t* xp32 = (uint32_t*)xp;
  {
    const float* xrow = x + b * 256 * 4096 + s0;
    float v0[8], v1[8];
#pragma unroll
    for (int it = 0; it < 8; ++it) {
      int item = tid + it * 1024;                 // 0..8191
      int pp = item & 63, dcol = item >> 6;       // dcol 0..127
      v0[it] = xrow[(2 * dcol) * 4096 + pp];
      v1[it] = xrow[(2 * dcol + 1) * 4096 + pp];
    }
#pragma unroll
    for (int it = 0; it < 8; ++it) {
      int item = tid + it * 1024;
      int pp = item & 63, dcol = item >> 6;
      xp32[pp * 148 + dcol] =
          (uint32_t)f2bf(v0[it]) | ((uint32_t)f2bf(v1[it]) << 16);
    }
    // tail cols: dcol 128 = (pos_y,pos_x), 129 = (1,0) bias, 130..135 = 0
    if (tid < 512) {
      int pp = tid & 63, dcol = 128 + (tid >> 6);
      float t0 = 0.f, t1 = 0.f;
      if (dcol == 128) { t0 = pos[s0 + pp]; t1 = pos[4096 + s0 + pp]; }
      else if (dcol == 129) { t0 = 1.0f; }
      xp32[pp * 148 + dcol] = (uint32_t)f2bf(t0) | ((uint32_t)f2bf(t1) << 16);
    }
  }
  if (tid < 256) boutL[tid] = bout[tid];
  for (int i = tid; i < 16 * QS; i += 1024) qbarL[i] = 0.f;
  __syncthreads();

// K-loop: depth-1 register prefetch of the A fragments (global->VGPR),
// B fragments from LDS. Fully unrolled => all ring indices static.
#define PHASE(WB, AI0, AI1) do {                                          \
    bf16x8 _A0 = (AI0), _A1 = (AI1);                                      \
    _Pragma("unroll")                                                     \
    for (int ks = 0; ks < NKS; ++ks) {                                    \
      bf16x8 _N0 = _A0, _N1 = _A1;                                        \
      if (ks + 1 < NKS) {                                                 \
        _N0 = *(const bf16x8*)((WB) + (ks + 1) * 512);                    \
        _N1 = *(const bf16x8*)((WB) + NKS * 512 + (ks + 1) * 512);        \
      }                                                                   \
      bf16x8 _b0 = *(const bf16x8*)&xp[px * KP + ks * 16 + q2 * 8];       \
      bf16x8 _b1 = *(const bf16x8*)&xp[(32 + px) * KP + ks * 16 + q2 * 8];\
      acc00 = __builtin_amdgcn_mfma_f32_32x32x16_bf16(_A0, _b0, acc00, 0, 0, 0); \
      acc01 = __builtin_amdgcn_mfma_f32_32x32x16_bf16(_A0, _b1, acc01, 0, 0, 0); \
      acc10 = __builtin_amdgcn_mfma_f32_32x32x16_bf16(_A1, _b0, acc10, 0, 0, 0); \
      acc11 = __builtin_amdgcn_mfma_f32_32x32x16_bf16(_A1, _b1, acc11, 0, 0, 0); \
      _A0 = _N0; _A1 = _N1;                                               \
    }                                                                     \
  } while (0)

  // ================= q phase =================
  f32x16 acc00 = (f32x16)0.f, acc01 = (f32x16)0.f,
         acc10 = (f32x16)0.f, acc11 = (f32x16)0.f;
  PHASE(wqf, A0, A1);

  // k-phase ks=0 preload: latency hides behind the norm section.
  bf16x8 K0 = *(const bf16x8*)(wkf);
  bf16x8 K1 = *(const bf16x8*)(wkf + NKS * 512);

  // normalize per m; accumulate qbar partials
  {
    float qsum[2][8];
#pragma unroll
    for (int nt = 0; nt < 2; ++nt)
#pragma unroll
      for (int r = 0; r < 8; ++r) qsum[nt][r] = 0.f;
#pragma unroll
    for (int ot = 0; ot < 2; ++ot) {
#pragma unroll
      for (int nt = 0; nt < 2; ++nt) {
        const f32x16 a = ot ? (nt ? acc11 : acc10) : (nt ? acc01 : acc00);
        float s20 = 0.f, s21 = 0.f;
#pragma unroll
        for (int r = 0; r < 8; ++r) {
          s20 = fmaf(a[r], a[r], s20);
          s21 = fmaf(a[r + 8], a[r + 8], s21);
        }
        s20 += __shfl_xor(s20, 32, 64);
        s21 += __shfl_xor(s21, 32, 64);
        float i0 = 1.0f / fmaxf(sqrtf(s20), EPSN);
        float i1 = 1.0f / fmaxf(sqrtf(s21), EPSN);
#pragma unroll
        for (int r = 0; r < 8; ++r) qsum[nt][r] += a[r] * i0 + a[r + 8] * i1;
      }
    }
#pragma unroll
    for (int nt = 0; nt < 2; ++nt)
#pragma unroll
      for (int r = 0; r < 8; ++r) {
        int j = (r & 3) + ((r >> 2) << 3) + (q2 << 2);
        atomicAdd(&qbarL[j * QS + nt * 32 + px], qsum[nt][r] * (1.0f / 64.0f));
      }
  }
  __syncthreads();

  // ================= k phase =================
  acc00 = (f32x16)0.f; acc01 = (f32x16)0.f;
  acc10 = (f32x16)0.f; acc11 = (f32x16)0.f;
  PHASE(wkf, K0, K1);

  {
    float qb[2][8];
#pragma unroll
    for (int nt = 0; nt < 2; ++nt)
#pragma unroll
      for (int r = 0; r < 8; ++r) {
        int j = (r & 3) + ((r >> 2) << 3) + (q2 << 2);
        qb[nt][r] = qbarL[j * QS + nt * 32 + px];
      }
#pragma unroll
    for (int ot = 0; ot < 2; ++ot) {
#pragma unroll
      for (int nt = 0; nt < 2; ++nt) {
        const f32x16 a = ot ? (nt ? acc11 : acc10) : (nt ? acc01 : acc00);
        float s20 = 0.f, s21 = 0.f, sp0 = 0.f, sp1 = 0.f;
#pragma unroll
        for (int r = 0; r < 8; ++r) {
          s20 = fmaf(a[r], a[r], s20);         sp0 = fmaf(qb[nt][r], a[r], sp0);
          s21 = fmaf(a[r + 8], a[r + 8], s21); sp1 = fmaf(qb[nt][r], a[r + 8], sp1);
        }
        s20 += __shfl_xor(s20, 32, 64);
        s21 += __shfl_xor(s21, 32, 64);
        sp0 += __shfl_xor(sp0, 32, 64);
        sp1 += __shfl_xor(sp1, 32, 64);
        if (q2 == 0) {
          int m0 = wid * 4 + ot * 2;
          attnM[(nt * 32 + px) * AT + m0]     = f2bf(sp0 / fmaxf(sqrtf(s20), EPSN));
          attnM[(nt * 32 + px) * AT + m0 + 1] = f2bf(sp1 / fmaxf(sqrtf(s21), EPSN));
        }
      }
    }
  }
  __syncthreads();

  // ================= epilogue: out = x + bout + WVt @ attn =================
  {
    const int otile = wid >> 1, pxt = wid & 1;
    f32x16 e = (f32x16)0.f;
    const unsigned short* wv = wsp + WVP_OFF + (otile * 32 + px) * 64 + q2 * 8;
    const unsigned short* ab = &attnM[(pxt * 32 + px) * AT + q2 * 8];
#pragma unroll
    for (int ks = 0; ks < 4; ++ks) {
      bf16x8 av = *(const bf16x8*)(wv + ks * 16);
      bf16x8 bv = *(const bf16x8*)(ab + ks * 16);
      e = __builtin_amdgcn_mfma_f32_32x32x16_bf16(av, bv, e, 0, 0, 0);
    }
#pragma unroll
    for (int r = 0; r < 16; ++r) {
      const int o = otile * 32 + (r & 3) + ((r >> 2) << 3) + (q2 << 2);
      const int p = pxt * 32 + px;
      const int gi = (b * 256 + o) * 4096 + s0 + p;
      out[gi] = x[gi] + boutL[o] + e[r];
    }
  }
#undef PHASE
}

// =====================================================================
extern "C" void kernel_launch(void* const* d_in, const int* in_sizes, int n_in,
                              void* d_out, int out_size, void* d_ws, size_t ws_size,
                              hipStream_t stream) {
  const float* x    = (const float*)d_in[0];
  const float* pos  = (const float*)d_in[1];
  const float* wq   = (const float*)d_in[2];
  const float* bq   = (const float*)d_in[3];
  const float* wk   = (const float*)d_in[4];
  const float* bk   = (const float*)d_in[5];
  const float* v    = (const float*)d_in[6];
  const float* wout = (const float*)d_in[7];
  const float* bout = (const float*)d_in[8];
  float* out = (float*)d_out;
  unsigned short* wsp = (unsigned short*)d_ws;

  hipLaunchKernelGGL(prep_kernel, dim3(1536), dim3(256), 0, stream,
                     wq, bq, wk, bk, v, wout, wsp);
  hipLaunchKernelGGL(fused_kernel, dim3(256), dim3(1024), 0, stream,
                     x, pos, wsp, bout, out);
}

// Round 2
// 128.407 us; speedup vs baseline: 1.0470x; 1.0470x over previous
//
#include <hip/hip_runtime.h>
#include <stdint.h>

#define EPSN 1e-12f

typedef float f32x16 __attribute__((ext_vector_type(16)));
typedef float f32x4 __attribute__((ext_vector_type(4)));
typedef __bf16 bf16x8 __attribute__((ext_vector_type(8)));

// ---- bf16 helpers (round-to-nearest-even) ----
__device__ __forceinline__ unsigned short f2bf(float f) {
  union { float f; unsigned int u; } v; v.f = f;
  unsigned int u = v.u + 0x7FFFu + ((v.u >> 16) & 1u);
  return (unsigned short)(u >> 16);
}

// ---- workspace layout (ushort offsets) ----
// Fragment-major packed weights for 32x32x16 MFMA, K padded 258(+bias)->272:
//   addr = ((tile*NKS + ks)*64 + hi*32 + col)*8 + j
//   value = W[o = tile*32 + col][k = ks*16 + hi*8 + j]  (k=258 bias, >258 zero)
#define NKS 17
#define WQF_OFF 0
#define WKF_OFF (32 * NKS * 64 * 8)
#define WVP_OFF (2 * 32 * NKS * 64 * 8)

// =====================================================================
// prep: blocks [0,512) pack wq/wk (4 o-rows each); [512,1536) WVt.
// =====================================================================
__global__ __launch_bounds__(256) void prep_kernel(
    const float* __restrict__ wq, const float* __restrict__ bq,
    const float* __restrict__ wk, const float* __restrict__ bk,
    const float* __restrict__ v, const float* __restrict__ wout,
    unsigned short* __restrict__ wsp) {
  int bid = blockIdx.x;
  if (bid < 512) {
    int isK = bid >= 256;
    int ob = (bid & 255) * 4;
    const float* w = isK ? wk : wq;
    const float* bb = isK ? bk : bq;
    unsigned short* dst = wsp + (isK ? WKF_OFF : WQF_OFF);
    // k 0..257 as 129 float2 per row
    for (int i = threadIdx.x; i < 4 * 129; i += 256) {
      int r = i / 129, q = i - r * 129;
      int o = ob + r, k = q * 2;
      float2 w2 = *(const float2*)(w + o * 258 + k);
      int g = o >> 5, col = o & 31;
      int ks = k >> 4, hi = (k >> 3) & 1, j = k & 7;
      uint32_t pk = (uint32_t)f2bf(w2.x) | ((uint32_t)f2bf(w2.y) << 16);
      *(uint32_t*)(dst + (((g * NKS + ks) * 64 + hi * 32 + col) << 3) + j) = pk;
    }
    // k 258 (bias) and 259..271 (zero)
    for (int i = threadIdx.x; i < 4 * 14; i += 256) {
      int r = i / 14, kk = 258 + (i - r * 14);
      int o = ob + r;
      int g = o >> 5, col = o & 31;
      int ks = kk >> 4, hi = (kk >> 3) & 1, j = kk & 7;
      dst[(((g * NKS + ks) * 64 + hi * 32 + col) << 3) + j] =
          (kk == 258) ? f2bf(bb[o]) : (unsigned short)0;
    }
  } else {
    int idx = (bid - 512) * 256 + threadIdx.x;  // [0, 262144)
    int fc = idx & 15, m = (idx >> 4) & 63, o = idx >> 10;
    const f32x4* wo = (const f32x4*)(wout + o * 256 + fc * 16);
    const f32x4* vm = (const f32x4*)(v + m * 256 + fc * 16);
    float s = 0.f;
#pragma unroll
    for (int f = 0; f < 4; ++f) {
      f32x4 a = wo[f], bvv = vm[f];
      s += a[0]*bvv[0] + a[1]*bvv[1] + a[2]*bvv[2] + a[3]*bvv[3];
    }
    s += __shfl_xor(s, 1, 64);
    s += __shfl_xor(s, 2, 64);
    s += __shfl_xor(s, 4, 64);
    s += __shfl_xor(s, 8, 64);
    if (fc == 0) wsp[WVP_OFF + o * 64 + m] = f2bf(s);
  }
}

// =====================================================================
// fused v3: 32 px/block, 512 blocks, 16 waves, 2 blocks/CU (8 waves/SIMD).
// Per wave: 2 o-tiles x 32 px => 2 accumulators (32 AGPR) so total regs
// fit the 64-reg / 8-wave budget. No software prefetch ring: TLP (8
// waves/SIMD + cross-block phase overlap) hides A-load and LDS latency.
// Mid-barrier moved after the k K-loop (k-MFMAs don't read qbarL).
// =====================================================================
#define PXB 32   // pixels per block
#define KP 296   // xp row stride in shorts
#define QS 34    // qbar row stride (floats)
#define AT 76    // attnM row stride (shorts)

__global__ __launch_bounds__(1024, 8) void fused_kernel(
    const float* __restrict__ x, const float* __restrict__ pos,
    const unsigned short* __restrict__ wsp, const float* __restrict__ bout,
    float* __restrict__ out) {
  __shared__ __align__(16) unsigned short xp[PXB * KP];        // 18944 B
  __shared__ __align__(16) float qbarL[16 * QS];               // 2176 B
  __shared__ __align__(16) unsigned short attnM[PXB * AT];     // 4864 B
  __shared__ float boutL[256];                                 // 1024 B

  const int tid = threadIdx.x;
  const int lane = tid & 63;
  const int wid = __builtin_amdgcn_readfirstlane(tid >> 6);
  const int px = lane & 31, q2 = lane >> 5;
  const int P0 = blockIdx.x * PXB;
  const int b = P0 >> 12, s0 = P0 & 4095;

  // Per-wave A-stream bases (tile0 = 2*wid, tile1 = 2*wid+1; +lane frag)
  const int wtoff = (2 * wid) * NKS * 512 + lane * 8;
  const unsigned short* wqf = wsp + WQF_OFF + wtoff;
  const unsigned short* wkf = wsp + WKF_OFF + wtoff;

  // ---- stage xp[p][c]: lanes along pixels => coalesced 128B segments ----
  uint32_t* xp32 = (uint32_t*)xp;
  {
    const float* xrow = x + b * 256 * 4096 + s0;
    float v0[4], v1[4];
#pragma unroll
    for (int it = 0; it < 4; ++it) {
      int item = tid + it * 1024;                 // 0..4095
      int pp = item & 31, dcol = item >> 5;       // dcol 0..127
      v0[it] = xrow[(2 * dcol) * 4096 + pp];
      v1[it] = xrow[(2 * dcol + 1) * 4096 + pp];
    }
#pragma unroll
    for (int it = 0; it < 4; ++it) {
      int item = tid + it * 1024;
      int pp = item & 31, dcol = item >> 5;
      xp32[pp * 148 + dcol] =
          (uint32_t)f2bf(v0[it]) | ((uint32_t)f2bf(v1[it]) << 16);
    }
    // tail cols: dcol 128 = (pos_y,pos_x), 129 = (1,0) bias, 130..135 = 0
    if (tid < 256) {
      int pp = tid & 31, dcol = 128 + (tid >> 5);
      float t0 = 0.f, t1 = 0.f;
      if (dcol == 128) { t0 = pos[s0 + pp]; t1 = pos[4096 + s0 + pp]; }
      else if (dcol == 129) { t0 = 1.0f; }
      xp32[pp * 148 + dcol] = (uint32_t)f2bf(t0) | ((uint32_t)f2bf(t1) << 16);
    }
  }
  if (tid < 256) boutL[tid] = bout[tid];
  for (int i = tid; i < 16 * QS; i += 1024) qbarL[i] = 0.f;
  __syncthreads();

// K-loop: 2 MFMAs per ks per wave; loads straight global(L2)->VGPR,
// compiler-scheduled within the 8-wave register budget.
#define PHASE(WB) do {                                                    \
    _Pragma("unroll")                                                     \
    for (int ks = 0; ks < NKS; ++ks) {                                    \
      bf16x8 _A0 = *(const bf16x8*)((WB) + ks * 512);                     \
      bf16x8 _A1 = *(const bf16x8*)((WB) + NKS * 512 + ks * 512);         \
      bf16x8 _b0 = *(const bf16x8*)&xp[px * KP + ks * 16 + q2 * 8];       \
      acc0 = __builtin_amdgcn_mfma_f32_32x32x16_bf16(_A0, _b0, acc0, 0, 0, 0); \
      acc1 = __builtin_amdgcn_mfma_f32_32x32x16_bf16(_A1, _b0, acc1, 0, 0, 0); \
    }                                                                     \
  } while (0)

  // ================= q phase =================
  f32x16 acc0 = (f32x16)0.f, acc1 = (f32x16)0.f;
  PHASE(wqf);

  // normalize per m; accumulate qbar partials
  {
    float qsum[8];
#pragma unroll
    for (int r = 0; r < 8; ++r) qsum[r] = 0.f;
#pragma unroll
    for (int ot = 0; ot < 2; ++ot) {
      const f32x16 a = ot ? acc1 : acc0;
      float s20 = 0.f, s21 = 0.f;
#pragma unroll
      for (int r = 0; r < 8; ++r) {
        s20 = fmaf(a[r], a[r], s20);
        s21 = fmaf(a[r + 8], a[r + 8], s21);
      }
      s20 += __shfl_xor(s20, 32, 64);
      s21 += __shfl_xor(s21, 32, 64);
      float i0 = 1.0f / fmaxf(sqrtf(s20), EPSN);
      float i1 = 1.0f / fmaxf(sqrtf(s21), EPSN);
#pragma unroll
      for (int r = 0; r < 8; ++r) qsum[r] += a[r] * i0 + a[r + 8] * i1;
    }
#pragma unroll
    for (int r = 0; r < 8; ++r) {
      int j = (r & 3) + ((r >> 2) << 3) + (q2 << 2);
      atomicAdd(&qbarL[j * QS + px], qsum[r] * (1.0f / 64.0f));
    }
  }
  // NO barrier here: k-phase MFMAs don't read qbarL; the barrier below
  // (after the k K-loop) orders the qbar atomics vs the qb reads.

  // ================= k phase =================
  acc0 = (f32x16)0.f; acc1 = (f32x16)0.f;
  PHASE(wkf);
  __syncthreads();

  {
    float qb[8];
#pragma unroll
    for (int r = 0; r < 8; ++r) {
      int j = (r & 3) + ((r >> 2) << 3) + (q2 << 2);
      qb[r] = qbarL[j * QS + px];
    }
#pragma unroll
    for (int ot = 0; ot < 2; ++ot) {
      const f32x16 a = ot ? acc1 : acc0;
      float s20 = 0.f, s21 = 0.f, sp0 = 0.f, sp1 = 0.f;
#pragma unroll
      for (int r = 0; r < 8; ++r) {
        s20 = fmaf(a[r], a[r], s20);         sp0 = fmaf(qb[r], a[r], sp0);
        s21 = fmaf(a[r + 8], a[r + 8], s21); sp1 = fmaf(qb[r], a[r + 8], sp1);
      }
      s20 += __shfl_xor(s20, 32, 64);
      s21 += __shfl_xor(s21, 32, 64);
      sp0 += __shfl_xor(sp0, 32, 64);
      sp1 += __shfl_xor(sp1, 32, 64);
      if (q2 == 0) {
        int m0 = wid * 4 + ot * 2;
        attnM[px * AT + m0]     = f2bf(sp0 / fmaxf(sqrtf(s20), EPSN));
        attnM[px * AT + m0 + 1] = f2bf(sp1 / fmaxf(sqrtf(s21), EPSN));
      }
    }
  }
  __syncthreads();

  // ================= epilogue: out = x + bout + WVt @ attn =================
  if (wid < 8) {
    const int otile = wid;
    f32x16 e = (f32x16)0.f;
    const unsigned short* wv = wsp + WVP_OFF + (otile * 32 + px) * 64 + q2 * 8;
    const unsigned short* ab = &attnM[px * AT + q2 * 8];
#pragma unroll
    for (int ks = 0; ks < 4; ++ks) {
      bf16x8 av = *(const bf16x8*)(wv + ks * 16);
      bf16x8 bv = *(const bf16x8*)(ab + ks * 16);
      e = __builtin_amdgcn_mfma_f32_32x32x16_bf16(av, bv, e, 0, 0, 0);
    }
#pragma unroll
    for (int r = 0; r < 16; ++r) {
      const int o = otile * 32 + (r & 3) + ((r >> 2) << 3) + (q2 << 2);
      const int gi = (b * 256 + o) * 4096 + s0 + px;
      out[gi] = x[gi] + boutL[o] + e[r];
    }
  }
#undef PHASE
}

// =====================================================================
extern "C" void kernel_launch(void* const* d_in, const int* in_sizes, int n_in,
                              void* d_out, int out_size, void* d_ws, size_t ws_size,
                              hipStream_t stream) {
  const float* x    = (const float*)d_in[0];
  const float* pos  = (const float*)d_in[1];
  const float* wq   = (const float*)d_in[2];
  const float* bq   = (const float*)d_in[3];
  const float* wk   = (const float*)d_in[4];
  const float* bk   = (const float*)d_in[5];
  const float* v    = (const float*)d_in[6];
  const float* wout = (const float*)d_in[7];
  const float* bout = (const float*)d_in[8];
  float* out = (float*)d_out;
  unsigned short* wsp = (unsigned short*)d_ws;

  hipLaunchKernelGGL(prep_kernel, dim3(1536), dim3(256), 0, stream,
                     wq, bq, wk, bk, v, wout, wsp);
  hipLaunchKernelGGL(fused_kernel, dim3(512), dim3(1024), 0, stream,
                     x, pos, wsp, bout, out);
}